// Round 23
// baseline (339.034 us; speedup 1.0000x reference)
//
#include <hip/hip_runtime.h>
#include <hip/hip_bf16.h>

// RSFConv2d round 23: 64-WIDE persistent-column ring conv.
//  Theory: R13-R22 showed per-step time is a ~fixed latency cost (~5us)
//  vs ~1.5us of work, and deepening the pipeline is compiler-blocked
//  (R17/R21 sank/spilled the carried loads). So make steps BIGGER:
//  tile 64-wide, 512 blocks x 512 threads (8 waves: wv&3=row-pair,
//  wv>>2=x-half). Ring = 18 rows x 66 px x 64B = 76KB static LDS
//  (gfx950 allows up to 160KB static; guide's 8-phase GEMM uses 128KB).
//  2x work per step against the same latency exposure; whole grid
//  co-resident (2 blocks/CU exactly, single generation); stage is
//  perfectly uniform (512 main units = 1/thread + 64 halo units).
//  All proven R18/R20 pieces verbatim: ring-slot algebra, px swizzle,
//  lgkm-only barrier, R13 phase order (loads->compute->cvt+ds_write->
//  nt stores->barrier), single-bf16 weights, XCD-bijective block map.
//  launch_bounds(512,4) = same 128-VGPR cap class as proven (256,2).

typedef __attribute__((ext_vector_type(8))) short bf16x8;
typedef __attribute__((ext_vector_type(16))) float f32x16;
typedef __attribute__((ext_vector_type(4))) unsigned int u32x4;
typedef __attribute__((ext_vector_type(4))) float f32x4v;

__device__ __forceinline__ unsigned short f2bf(float f) {
    unsigned u = __float_as_uint(f);
    u = u + 0x7fffu + ((u >> 16) & 1u);  // RNE
    return (unsigned short)(u >> 16);
}
__device__ __forceinline__ float bf2f(unsigned short b) {
    return __uint_as_float(((unsigned)b) << 16);
}

// lgkm-only barrier (validated through timing replay in R14/R16/R18/R20/R22).
__device__ __forceinline__ void lgkm_barrier() {
    asm volatile("s_waitcnt lgkmcnt(0)" ::: "memory");
    __builtin_amdgcn_s_barrier();
    __builtin_amdgcn_sched_barrier(0);
}

// ---------------- kernel synthesis: one thread per (o,i) pair ----------------
__global__ __launch_bounds__(256) void prep_kernel(const float* __restrict__ fw,
                                                   unsigned short* __restrict__ wbuf)
{
    int gid = blockIdx.x * blockDim.x + threadIdx.x;
    if (gid >= 32 * 32) return;
    int o = gid >> 5;
    int i = gid & 31;

    const float* f = fw + (size_t)gid * 12;
    float re[3][2], im[3][2];
#pragma unroll
    for (int ky = 0; ky < 3; ++ky)
#pragma unroll
        for (int kx = 0; kx < 2; ++kx) {
            re[ky][kx] = f[(ky * 2 + kx) * 2 + 0];
            im[ky][kx] = f[(ky * 2 + kx) * 2 + 1];
        }

    const float c3[3] = {1.f, -0.5f, -0.5f};
    const float s3[3] = {0.f, 0.86602540378443864676f, -0.86602540378443864676f};

    float base[3][3];
#pragma unroll
    for (int y = 0; y < 3; ++y)
#pragma unroll
        for (int x = 0; x < 3; ++x) {
            float sum = 0.f;
#pragma unroll
            for (int ky = 0; ky < 3; ++ky)
#pragma unroll
                for (int kx = 0; kx < 3; ++kx) {
                    float rf, mf;
                    if (kx < 2) {
                        rf = re[ky][kx];
                        mf = im[ky][kx];
                    } else {
                        int kys = (3 - ky) % 3;
                        rf = re[kys][1];
                        mf = -im[kys][1];
                    }
                    int m = (ky * y + kx * x) % 3;
                    sum += rf * c3[m] - mf * s3[m];
                }
            base[y][x] = sum * (1.f / 9.f);
        }

    // cos/sin(r*pi/4) exact tables (no on-device transcendentals)
    const float S2 = 0.70710678118654752440f;
    const float ctab[8] = {1.f, S2, 0.f, -S2, -1.f, -S2, 0.f, S2};
    const float stab[8] = {0.f, S2, 1.f, S2, 0.f, -S2, -1.f, -S2};
    const float scales[4] = {1.f, 1.25f, 1.5625f, 1.953125f};
    const float coords[3] = {-2.f / 3.f, 0.f, 2.f / 3.f};

    float acc[3][3] = {{0.f, 0.f, 0.f}, {0.f, 0.f, 0.f}, {0.f, 0.f, 0.f}};

    for (int t = 0; t < 32; ++t) {
        int r = t >> 2, si = t & 3;
        float sc = scales[si];
        float c = ctab[r] * sc;
        float s = stab[r] * sc;
#pragma unroll
        for (int p = 0; p < 3; ++p) {
#pragma unroll
            for (int q = 0; q < 3; ++q) {
                float gxo = coords[q], gyo = coords[p];
                float gx = c * gxo - s * gyo;
                float gy = s * gxo + c * gyo;
                float ix = ((gx + 1.f) * 3.f - 1.f) * 0.5f;
                float iy = ((gy + 1.f) * 3.f - 1.f) * 0.5f;
                float fx0 = floorf(ix), fy0 = floorf(iy);
                int x0 = (int)fx0, y0 = (int)fy0;
                int x1 = x0 + 1, y1 = y0 + 1;
                float wx1 = ix - fx0, wy1 = iy - fy0;
                float wx0 = 1.f - wx1, wy0 = 1.f - wy1;

                float v = 0.f;
                {
                    int yc = min(max(y0, 0), 2), xc = min(max(x0, 0), 2);
                    bool ok = (x0 >= 0) & (x0 < 3) & (y0 >= 0) & (y0 < 3);
                    v += (ok ? base[yc][xc] : 0.f) * (wy0 * wx0);
                }
                {
                    int yc = min(max(y0, 0), 2), xc = min(max(x1, 0), 2);
                    bool ok = (x1 >= 0) & (x1 < 3) & (y0 >= 0) & (y0 < 3);
                    v += (ok ? base[yc][xc] : 0.f) * (wy0 * wx1);
                }
                {
                    int yc = min(max(y1, 0), 2), xc = min(max(x0, 0), 2);
                    bool ok = (x0 >= 0) & (x0 < 3) & (y1 >= 0) & (y1 < 3);
                    v += (ok ? base[yc][xc] : 0.f) * (wy1 * wx0);
                }
                {
                    int yc = min(max(y1, 0), 2), xc = min(max(x1, 0), 2);
                    bool ok = (x1 >= 0) & (x1 < 3) & (y1 >= 0) & (y1 < 3);
                    v += (ok ? base[yc][xc] : 0.f) * (wy1 * wx1);
                }
                acc[p][q] += v;
            }
        }
    }

    // wbuf[(tap*2+hl)*1024 + o*32 + i]; conv uses hl=0 (wh) only.
#pragma unroll
    for (int p = 0; p < 3; ++p)
#pragma unroll
        for (int q = 0; q < 3; ++q) {
            int t = p * 3 + q;
            float w = acc[p][q] * (1.f / 32.f);
            unsigned short wh = f2bf(w);
            unsigned short wl = f2bf(w - bf2f(wh));
            size_t b = (size_t)(t * 2) * 1024 + o * 32 + i;
            wbuf[b] = wh;
            wbuf[b + 1024] = wl;
        }
}

// ---------------- persistent ring conv, 64-wide ----------------
#define ROWB 4224   // 66 px-slots x 64 B (px 0..63 main, 64=left halo, 65=right)
#define RING 18     // 18 rows x 4224 B = 76032 B

// swizzle slot: any 8 consecutive px cover all 8 16B phases
__device__ __forceinline__ unsigned swz(int px, int c) {
    return ((unsigned)px << 6) + ((((unsigned)(px >> 1) & 3u) ^ (unsigned)c) << 4);
}

__global__ __launch_bounds__(512, 4) void conv_wide(const float* __restrict__ x,
                                                    const unsigned short* __restrict__ wbuf,
                                                    float* __restrict__ out)
{
    __shared__ char lds[RING * ROWB];  // 76032 B -> 2 blocks/CU (152KB of 160KB)

    const int lin = blockIdx.x;     // 512 blocks: XCD k = image k
    const int n = lin & 7;
    const int idx = lin >> 3;       // 0..63
    const int xt = idx & 7;
    const int yseg = idx >> 3;
    const int x0t = xt * 64;
    const int Y0 = yseg * 64;

    const int tid = threadIdx.x;
    const int lane = tid & 63;
    const int wv = tid >> 6;        // 0..7
    const int pxl = lane & 31;
    const int kh = lane >> 5;
    const int rw = wv & 3;          // row-pair within band
    const int xh = wv >> 2;         // x-half
    const int r0 = rw << 1;
    const int pxbase = xh << 5;

    const float* xn = x + ((size_t)n << 23);

    // ---- A fragments (wh only), loop-invariant: 18 x bf16x8 = 72 VGPR ----
    bf16x8 A[3][3][2];  // [dy][dx][ks]
#pragma unroll
    for (int dy = 0; dy < 3; ++dy)
#pragma unroll
        for (int dx = 0; dx < 3; ++dx)
#pragma unroll
            for (int ks = 0; ks < 2; ++ks)
                A[dy][dx][ks] = *(const bf16x8*)(
                    wbuf + (size_t)((dy * 3 + dx) * 2) * 1024 +
                    pxl * 32 + ks * 16 + kh * 8);

    // ---- per-lane read column offsets (main 0..63, left halo 64, right 65) ----
    int coff[3];
#pragma unroll
    for (int dx = 0; dx < 3; ++dx) {
        int v = dx + pxbase + pxl - 1;
        int pl = (v < 0) ? 64 : ((v == 64) ? 65 : v);
        coff[dx] = (int)swz(pl, kh);
    }

    // ---- stage-unit geometry (loop-invariant) ----
    // main (512 units, 1/thread): row=tid>>6 (0..7), q=(tid&63)>>2 (0..15), c=tid&3
    // halo (tid<64): hr=tid>>3 (0..7), hside=(tid>>2)&1, hc=tid&3
    const int r0s = tid >> 6, q0 = (tid & 63) >> 2, c0 = tid & 3;
    const int hr = tid >> 3, hside = (tid >> 2) & 1, hc = tid & 3;
    const bool hk = (tid < 64);

    // ---- ring slot state ----
    int sl[4];
#pragma unroll
    for (int m = 0; m < 4; ++m) sl[m] = (Y0 + r0 + m) % 18;
    int wb = (Y0 + 10) % 18;

    // ---- prologue: stage rows Y0-1 .. Y0+8 (10 rows): 640 main + 80 halo ----
    const int p0 = Y0 % 18;
    for (int u = tid; u < 720; u += 512) {
        if (u < 640) {
            int row = u >> 6, rem = u & 63, q = rem >> 2, c = rem & 3;
            int gy = Y0 - 1 + row;
            bool ok = (unsigned)gy < 512u;
            const float* src = xn + (((size_t)(c * 8)) << 18) + ((ok ? gy : 0) << 9) +
                               x0t + (q << 2);
            float v[8][4];
#pragma unroll
            for (int cc = 0; cc < 8; ++cc) {
                f32x4v ld = *(const f32x4v*)(src + ((size_t)cc << 18));
#pragma unroll
                for (int j = 0; j < 4; ++j) v[cc][j] = ok ? ld[j] : 0.f;
            }
            int slot = p0 + row; if (slot >= 18) slot -= 18;
            int px0 = (q << 2);
#pragma unroll
            for (int j = 0; j < 4; ++j) {
                u32x4 d;
#pragma unroll
                for (int p = 0; p < 4; ++p)
                    d[p] = (unsigned)f2bf(v[2 * p][j]) | ((unsigned)f2bf(v[2 * p + 1][j]) << 16);
                *(u32x4*)(lds + slot * ROWB + swz(px0 + j, c)) = d;
            }
        } else {
            int hu2 = u - 640;
            int row = hu2 >> 3, side = (hu2 >> 2) & 1, c = hu2 & 3;
            int gy = Y0 - 1 + row;
            int gx = x0t + (side ? 64 : -1);
            bool ok = ((unsigned)gy < 512u) & ((unsigned)gx < 512u);
            const float* src = xn + (((size_t)(c * 8)) << 18) +
                               ((ok ? gy : 0) << 9) + (ok ? gx : 0);
            u32x4 d;
#pragma unroll
            for (int p = 0; p < 4; ++p) {
                float a = ok ? src[(size_t)(2 * p) << 18] : 0.f;
                float b = ok ? src[(size_t)(2 * p + 1) << 18] : 0.f;
                d[p] = (unsigned)f2bf(a) | ((unsigned)f2bf(b) << 16);
            }
            int slot = p0 + row; if (slot >= 18) slot -= 18;
            *(u32x4*)(lds + slot * ROWB + swz(64 + side, c)) = d;
        }
    }
    lgkm_barrier();

    // ---- 8 steps of 8 output rows (x 64 cols) ----
#pragma unroll 1
    for (int t = 0; t < 8; ++t) {
        const int R = Y0 + (t << 3);
        const bool st = (t < 7);

        // -- issue loads for the 8 NEW rows of band t+1 (gy = R+9 .. R+16) --
        f32x4v L0[8];
        float H[8];
        bool ok0 = false, okh = false;
        if (st) {
            int gy = R + 9 + r0s;
            ok0 = (unsigned)gy < 512u;
            const float* src = xn + (((size_t)(c0 * 8)) << 18) + ((ok0 ? gy : 0) << 9) +
                               x0t + (q0 << 2);
#pragma unroll
            for (int cc = 0; cc < 8; ++cc) L0[cc] = *(const f32x4v*)(src + ((size_t)cc << 18));
            if (hk) {
                int gy1 = R + 9 + hr;
                int gx = x0t + (hside ? 64 : -1);
                okh = ((unsigned)gy1 < 512u) & ((unsigned)gx < 512u);
                const float* s1 = xn + (((size_t)(hc * 8)) << 18) +
                                  ((okh ? gy1 : 0) << 9) + (okh ? gx : 0);
#pragma unroll
                for (int cc = 0; cc < 8; ++cc) H[cc] = s1[(size_t)cc << 18];
            }
        }
        __builtin_amdgcn_sched_barrier(0);  // loads issue BEFORE compute

        // -- compute band t: out rows R+r0+{0,1}, cols x0t+pxbase+pxl --
        f32x16 acc[2];
#pragma unroll
        for (int f = 0; f < 2; ++f)
#pragma unroll
            for (int r = 0; r < 16; ++r) acc[f][r] = 0.f;

#pragma unroll
        for (int m = 0; m < 4; ++m) {
            bf16x8 b[3][2];
#pragma unroll
            for (int dx = 0; dx < 3; ++dx)
#pragma unroll
                for (int ks = 0; ks < 2; ++ks)
                    b[dx][ks] = *(const bf16x8*)(lds + sl[m] * ROWB +
                                                 (unsigned)(coff[dx] ^ (ks << 5)));
#pragma unroll
            for (int f = 0; f < 2; ++f) {
                const int dy = m - f;
                if (dy >= 0 && dy < 3) {
#pragma unroll
                    for (int dx = 0; dx < 3; ++dx)
#pragma unroll
                        for (int ks = 0; ks < 2; ++ks)
                            acc[f] = __builtin_amdgcn_mfma_f32_32x32x16_bf16(
                                A[dy][dx][ks], b[dx][ks], acc[f], 0, 0, 0);
                }
            }
        }

        // -- cvt + ring writes for band t+1 (8 disjoint slots; loads oldest) --
        if (st) {
            {
                int slot = wb + r0s; if (slot >= 18) slot -= 18;
                int px0 = (q0 << 2);
#pragma unroll
                for (int j = 0; j < 4; ++j) {
                    u32x4 d;
#pragma unroll
                    for (int p = 0; p < 4; ++p) {
                        float a = ok0 ? L0[2 * p][j] : 0.f;
                        float b2 = ok0 ? L0[2 * p + 1][j] : 0.f;
                        d[p] = (unsigned)f2bf(a) | ((unsigned)f2bf(b2) << 16);
                    }
                    *(u32x4*)(lds + slot * ROWB + swz(px0 + j, c0)) = d;
                }
            }
            if (hk) {
                int slot = wb + hr; if (slot >= 18) slot -= 18;
                u32x4 d;
#pragma unroll
                for (int p = 0; p < 4; ++p) {
                    float a = okh ? H[2 * p] : 0.f;
                    float b2 = okh ? H[2 * p + 1] : 0.f;
                    d[p] = (unsigned)f2bf(a) | ((unsigned)f2bf(b2) << 16);
                }
                *(u32x4*)(lds + slot * ROWB + swz(64 + hside, hc)) = d;
            }
        }

        // -- stores LAST: nontemporal (plain stores regressed replay in R19) --
#pragma unroll
        for (int f = 0; f < 2; ++f) {
            int gy = R + r0 + f;
#pragma unroll
            for (int reg = 0; reg < 16; ++reg) {
                int o = (reg & 3) + 8 * (reg >> 2) + 4 * kh;
                size_t oidx = ((size_t)(n * 32 + o) << 18) + ((size_t)gy << 9) +
                              x0t + pxbase + pxl;
                __builtin_nontemporal_store(acc[f][reg], &out[oidx]);
            }
        }

        lgkm_barrier();

        // -- advance ring slots by 8 mod 18 --
#pragma unroll
        for (int m = 0; m < 4; ++m) {
            sl[m] += 8; if (sl[m] >= 18) sl[m] -= 18;
        }
        wb += 8; if (wb >= 18) wb -= 18;
    }
}

extern "C" void kernel_launch(void* const* d_in, const int* in_sizes, int n_in,
                              void* d_out, int out_size, void* d_ws, size_t ws_size,
                              hipStream_t stream) {
    const float* x = (const float*)d_in[0];
    const float* fw = (const float*)d_in[1];
    float* out = (float*)d_out;
    unsigned short* wbuf = (unsigned short*)d_ws;  // 18*1024 bf16 = 36864 B

    prep_kernel<<<dim3(4), 256, 0, stream>>>(fw, wbuf);
    conv_wide<<<dim3(512), 512, 0, stream>>>(x, wbuf, out);
}

// Round 24
// 152.237 us; speedup vs baseline: 2.2270x; 2.2270x over previous
//
#include <hip/hip_runtime.h>
#include <hip/hip_bf16.h>

// RSFConv2d FINAL (= R18/R20/R22, proven best: 153.2-153.9us across 3 runs).
//  Persistent-column MFMA conv: 1024 blocks (8n x 16xt x 8yseg,
//  XCD-bijective), each walks 64 output rows in 8 steps of 8 rows through an
//  18-row LDS ring (39.2KB, bank-swizzled). Per step: issue next-band loads
//  -> 36x mfma_f32_32x32x16_bf16 (A-frags resident in regs) -> cvt+ring
//  ds_write -> nontemporal stores -> lgkm-only barrier (no vmcnt drain).
//  Weights: single-bf16 (RNE) from prep (irfft2 + 32x rot/scale grid-sample
//  mean, exact trig tables); x converted to bf16 during staging.
//  Falsified alternatives (do not retry):
//   - 64-wide tile / 512 thr: VGPR budget 64 -> A-frags spill, FETCH 4.6x (R23)
//   - deeper reg pipeline: compiler sinks loads / spills (R17, R21)
//   - launch_bounds(256,3): post-timing race (R15)
//   - plain stores: dirty-L2 writeback floods graph replays (R19, +34us)
//   - stores-before-cvt: in-order vmcnt drains stores at the load-wait (R14)
//   - vmcnt(0) barrier: +18us (R13 vs R16)
//  History: 855 (fp32 direct) -> 536 -> 414 -> 237 -> 202 -> 191 -> 154.

typedef __attribute__((ext_vector_type(8))) short bf16x8;
typedef __attribute__((ext_vector_type(16))) float f32x16;
typedef __attribute__((ext_vector_type(4))) unsigned int u32x4;
typedef __attribute__((ext_vector_type(4))) float f32x4v;

__device__ __forceinline__ unsigned short f2bf(float f) {
    unsigned u = __float_as_uint(f);
    u = u + 0x7fffu + ((u >> 16) & 1u);  // RNE
    return (unsigned short)(u >> 16);
}
__device__ __forceinline__ float bf2f(unsigned short b) {
    return __uint_as_float(((unsigned)b) << 16);
}

// lgkm-only barrier (validated through timing replay in R14/R16/R18/R20/R22).
__device__ __forceinline__ void lgkm_barrier() {
    asm volatile("s_waitcnt lgkmcnt(0)" ::: "memory");
    __builtin_amdgcn_s_barrier();
    __builtin_amdgcn_sched_barrier(0);
}

// ---------------- kernel synthesis: one thread per (o,i) pair ----------------
__global__ __launch_bounds__(256) void prep_kernel(const float* __restrict__ fw,
                                                   unsigned short* __restrict__ wbuf)
{
    int gid = blockIdx.x * blockDim.x + threadIdx.x;
    if (gid >= 32 * 32) return;
    int o = gid >> 5;
    int i = gid & 31;

    const float* f = fw + (size_t)gid * 12;
    float re[3][2], im[3][2];
#pragma unroll
    for (int ky = 0; ky < 3; ++ky)
#pragma unroll
        for (int kx = 0; kx < 2; ++kx) {
            re[ky][kx] = f[(ky * 2 + kx) * 2 + 0];
            im[ky][kx] = f[(ky * 2 + kx) * 2 + 1];
        }

    const float c3[3] = {1.f, -0.5f, -0.5f};
    const float s3[3] = {0.f, 0.86602540378443864676f, -0.86602540378443864676f};

    float base[3][3];
#pragma unroll
    for (int y = 0; y < 3; ++y)
#pragma unroll
        for (int x = 0; x < 3; ++x) {
            float sum = 0.f;
#pragma unroll
            for (int ky = 0; ky < 3; ++ky)
#pragma unroll
                for (int kx = 0; kx < 3; ++kx) {
                    float rf, mf;
                    if (kx < 2) {
                        rf = re[ky][kx];
                        mf = im[ky][kx];
                    } else {
                        int kys = (3 - ky) % 3;
                        rf = re[kys][1];
                        mf = -im[kys][1];
                    }
                    int m = (ky * y + kx * x) % 3;
                    sum += rf * c3[m] - mf * s3[m];
                }
            base[y][x] = sum * (1.f / 9.f);
        }

    // cos/sin(r*pi/4) exact tables (no on-device transcendentals)
    const float S2 = 0.70710678118654752440f;
    const float ctab[8] = {1.f, S2, 0.f, -S2, -1.f, -S2, 0.f, S2};
    const float stab[8] = {0.f, S2, 1.f, S2, 0.f, -S2, -1.f, -S2};
    const float scales[4] = {1.f, 1.25f, 1.5625f, 1.953125f};
    const float coords[3] = {-2.f / 3.f, 0.f, 2.f / 3.f};

    float acc[3][3] = {{0.f, 0.f, 0.f}, {0.f, 0.f, 0.f}, {0.f, 0.f, 0.f}};

    for (int t = 0; t < 32; ++t) {
        int r = t >> 2, si = t & 3;
        float sc = scales[si];
        float c = ctab[r] * sc;
        float s = stab[r] * sc;
#pragma unroll
        for (int p = 0; p < 3; ++p) {
#pragma unroll
            for (int q = 0; q < 3; ++q) {
                float gxo = coords[q], gyo = coords[p];
                float gx = c * gxo - s * gyo;
                float gy = s * gxo + c * gyo;
                float ix = ((gx + 1.f) * 3.f - 1.f) * 0.5f;
                float iy = ((gy + 1.f) * 3.f - 1.f) * 0.5f;
                float fx0 = floorf(ix), fy0 = floorf(iy);
                int x0 = (int)fx0, y0 = (int)fy0;
                int x1 = x0 + 1, y1 = y0 + 1;
                float wx1 = ix - fx0, wy1 = iy - fy0;
                float wx0 = 1.f - wx1, wy0 = 1.f - wy1;

                float v = 0.f;
                {
                    int yc = min(max(y0, 0), 2), xc = min(max(x0, 0), 2);
                    bool ok = (x0 >= 0) & (x0 < 3) & (y0 >= 0) & (y0 < 3);
                    v += (ok ? base[yc][xc] : 0.f) * (wy0 * wx0);
                }
                {
                    int yc = min(max(y0, 0), 2), xc = min(max(x1, 0), 2);
                    bool ok = (x1 >= 0) & (x1 < 3) & (y0 >= 0) & (y0 < 3);
                    v += (ok ? base[yc][xc] : 0.f) * (wy0 * wx1);
                }
                {
                    int yc = min(max(y1, 0), 2), xc = min(max(x0, 0), 2);
                    bool ok = (x0 >= 0) & (x0 < 3) & (y1 >= 0) & (y1 < 3);
                    v += (ok ? base[yc][xc] : 0.f) * (wy1 * wx0);
                }
                {
                    int yc = min(max(y1, 0), 2), xc = min(max(x1, 0), 2);
                    bool ok = (x1 >= 0) & (x1 < 3) & (y1 >= 0) & (y1 < 3);
                    v += (ok ? base[yc][xc] : 0.f) * (wy1 * wx1);
                }
                acc[p][q] += v;
            }
        }
    }

    // wbuf[(tap*2+hl)*1024 + o*32 + i]; conv uses hl=0 (wh) only.
#pragma unroll
    for (int p = 0; p < 3; ++p)
#pragma unroll
        for (int q = 0; q < 3; ++q) {
            int t = p * 3 + q;
            float w = acc[p][q] * (1.f / 32.f);
            unsigned short wh = f2bf(w);
            unsigned short wl = f2bf(w - bf2f(wh));
            size_t b = (size_t)(t * 2) * 1024 + o * 32 + i;
            wbuf[b] = wh;
            wbuf[b + 1024] = wl;
        }
}

// ---------------- persistent ring conv ----------------
#define ROWB 2176   // 34 px-slots x 64 B (px 0..31 main, 32=left halo, 33=right)
#define RING 18     // 18 rows x 2176 B = 39168 B

// swizzle slot: any 8 consecutive px cover all 8 16B phases
__device__ __forceinline__ unsigned swz(int px, int c) {
    return ((unsigned)px << 6) + ((((unsigned)(px >> 1) & 3u) ^ (unsigned)c) << 4);
}

__global__ __launch_bounds__(256, 2) void conv_pipe(const float* __restrict__ x,
                                                    const unsigned short* __restrict__ wbuf,
                                                    float* __restrict__ out)
{
    __shared__ char lds[RING * ROWB];  // 39168 B

    const int lin = blockIdx.x;     // 1024 blocks: XCD k = image k
    const int n = lin & 7;
    const int idx = lin >> 3;
    const int xt = idx & 15;
    const int yseg = idx >> 4;
    const int x0t = xt * 32;
    const int Y0 = yseg * 64;

    const int tid = threadIdx.x;
    const int lane = tid & 63;
    const int wv = tid >> 6;
    const int pxl = lane & 31;
    const int kh = lane >> 5;

    const float* xn = x + ((size_t)n << 23);

    // ---- A fragments (wh only), loop-invariant: 18 x bf16x8 = 72 VGPR ----
    bf16x8 A[3][3][2];  // [dy][dx][ks]
#pragma unroll
    for (int dy = 0; dy < 3; ++dy)
#pragma unroll
        for (int dx = 0; dx < 3; ++dx)
#pragma unroll
            for (int ks = 0; ks < 2; ++ks)
                A[dy][dx][ks] = *(const bf16x8*)(
                    wbuf + (size_t)((dy * 3 + dx) * 2) * 1024 +
                    pxl * 32 + ks * 16 + kh * 8);

    // ---- per-lane read column offsets (main 0..31, left halo 32, right 33) ----
    int coff[3];
#pragma unroll
    for (int dx = 0; dx < 3; ++dx) {
        int v = dx + pxl - 1;
        int pl = (v < 0) ? 32 : ((v == 32) ? 33 : v);
        coff[dx] = (int)swz(pl, kh);
    }

    // ---- stage-unit geometry (loop-invariant) ----
    const int r0s = tid >> 5, q0 = (tid >> 2) & 7, c0 = tid & 3;
    const int hr = tid >> 3, hside = (tid >> 2) & 1, hc = tid & 3;  // tid<64
    const bool hk = (tid < 64);

    // ---- ring slot state ----
    int sl[4];
#pragma unroll
    for (int m = 0; m < 4; ++m) sl[m] = (Y0 + (wv << 1) + m) % 18;
    int wb = (Y0 + 10) % 18;

    // ---- prologue: stage rows Y0-1 .. Y0+8 (10 rows) ----
    const int p0 = Y0 % 18;
    for (int u = tid; u < 400; u += 256) {
        if (u < 320) {
            int row = u >> 5, q = (u >> 2) & 7, c = u & 3;
            int gy = Y0 - 1 + row;
            bool ok = (unsigned)gy < 512u;
            const float* src = xn + (((size_t)(c * 8)) << 18) + ((ok ? gy : 0) << 9) +
                               x0t + (q << 2);
            float v[8][4];
#pragma unroll
            for (int cc = 0; cc < 8; ++cc) {
                f32x4v ld = *(const f32x4v*)(src + ((size_t)cc << 18));
#pragma unroll
                for (int j = 0; j < 4; ++j) v[cc][j] = ok ? ld[j] : 0.f;
            }
            int slot = p0 + row; if (slot >= 18) slot -= 18;
            int px0 = (q << 2);
#pragma unroll
            for (int j = 0; j < 4; ++j) {
                u32x4 d;
#pragma unroll
                for (int p = 0; p < 4; ++p)
                    d[p] = (unsigned)f2bf(v[2 * p][j]) | ((unsigned)f2bf(v[2 * p + 1][j]) << 16);
                *(u32x4*)(lds + slot * ROWB + swz(px0 + j, c)) = d;
            }
        } else {
            int hu2 = u - 320;
            int row = hu2 >> 3, side = (hu2 >> 2) & 1, c = hu2 & 3;
            int gy = Y0 - 1 + row;
            int gx = x0t + (side ? 32 : -1);
            bool ok = ((unsigned)gy < 512u) & ((unsigned)gx < 512u);
            const float* src = xn + (((size_t)(c * 8)) << 18) +
                               ((ok ? gy : 0) << 9) + (ok ? gx : 0);
            u32x4 d;
#pragma unroll
            for (int p = 0; p < 4; ++p) {
                float a = ok ? src[(size_t)(2 * p) << 18] : 0.f;
                float b = ok ? src[(size_t)(2 * p + 1) << 18] : 0.f;
                d[p] = (unsigned)f2bf(a) | ((unsigned)f2bf(b) << 16);
            }
            int slot = p0 + row; if (slot >= 18) slot -= 18;
            *(u32x4*)(lds + slot * ROWB + swz(32 + side, c)) = d;
        }
    }
    lgkm_barrier();

    // ---- 8 steps of 8 output rows ----
#pragma unroll 1
    for (int t = 0; t < 8; ++t) {
        const int R = Y0 + (t << 3);
        const bool st = (t < 7);

        // -- issue loads for the 8 NEW rows of band t+1 (gy = R+9 .. R+16) --
        f32x4v L0[8];
        float H[8];
        bool ok0 = false, okh = false;
        if (st) {
            int gy = R + 9 + r0s;
            ok0 = (unsigned)gy < 512u;
            const float* src = xn + (((size_t)(c0 * 8)) << 18) + ((ok0 ? gy : 0) << 9) +
                               x0t + (q0 << 2);
#pragma unroll
            for (int cc = 0; cc < 8; ++cc) L0[cc] = *(const f32x4v*)(src + ((size_t)cc << 18));
            if (hk) {
                int gy1 = R + 9 + hr;
                int gx = x0t + (hside ? 32 : -1);
                okh = ((unsigned)gy1 < 512u) & ((unsigned)gx < 512u);
                const float* s1 = xn + (((size_t)(hc * 8)) << 18) +
                                  ((okh ? gy1 : 0) << 9) + (okh ? gx : 0);
#pragma unroll
                for (int cc = 0; cc < 8; ++cc) H[cc] = s1[(size_t)cc << 18];
            }
        }
        __builtin_amdgcn_sched_barrier(0);  // loads issue BEFORE compute

        // -- compute band t: out rows R+2wv+{0,1} --
        f32x16 acc[2];
#pragma unroll
        for (int f = 0; f < 2; ++f)
#pragma unroll
            for (int r = 0; r < 16; ++r) acc[f][r] = 0.f;

#pragma unroll
        for (int m = 0; m < 4; ++m) {
            bf16x8 b[3][2];
#pragma unroll
            for (int dx = 0; dx < 3; ++dx)
#pragma unroll
                for (int ks = 0; ks < 2; ++ks)
                    b[dx][ks] = *(const bf16x8*)(lds + sl[m] * ROWB +
                                                 (unsigned)(coff[dx] ^ (ks << 5)));
#pragma unroll
            for (int f = 0; f < 2; ++f) {
                const int dy = m - f;
                if (dy >= 0 && dy < 3) {
#pragma unroll
                    for (int dx = 0; dx < 3; ++dx)
#pragma unroll
                        for (int ks = 0; ks < 2; ++ks)
                            acc[f] = __builtin_amdgcn_mfma_f32_32x32x16_bf16(
                                A[dy][dx][ks], b[dx][ks], acc[f], 0, 0, 0);
                }
            }
        }

        // -- cvt + ring writes for band t+1 (8 disjoint slots; loads oldest) --
        if (st) {
            {
                int slot = wb + r0s; if (slot >= 18) slot -= 18;
                int px0 = (q0 << 2);
#pragma unroll
                for (int j = 0; j < 4; ++j) {
                    u32x4 d;
#pragma unroll
                    for (int p = 0; p < 4; ++p) {
                        float a = ok0 ? L0[2 * p][j] : 0.f;
                        float b2 = ok0 ? L0[2 * p + 1][j] : 0.f;
                        d[p] = (unsigned)f2bf(a) | ((unsigned)f2bf(b2) << 16);
                    }
                    *(u32x4*)(lds + slot * ROWB + swz(px0 + j, c0)) = d;
                }
            }
            if (hk) {
                int slot = wb + hr; if (slot >= 18) slot -= 18;
                u32x4 d;
#pragma unroll
                for (int p = 0; p < 4; ++p) {
                    float a = okh ? H[2 * p] : 0.f;
                    float b2 = okh ? H[2 * p + 1] : 0.f;
                    d[p] = (unsigned)f2bf(a) | ((unsigned)f2bf(b2) << 16);
                }
                *(u32x4*)(lds + slot * ROWB + swz(32 + hside, hc)) = d;
            }
        }

        // -- stores LAST: nontemporal (write-through; keeps graph replays
        //    clean -- plain stores regressed timed total by 34us in R19) --
#pragma unroll
        for (int f = 0; f < 2; ++f) {
            int gy = R + (wv << 1) + f;
#pragma unroll
            for (int reg = 0; reg < 16; ++reg) {
                int o = (reg & 3) + 8 * (reg >> 2) + 4 * kh;
                size_t oidx = ((size_t)(n * 32 + o) << 18) + ((size_t)gy << 9) + x0t + pxl;
                __builtin_nontemporal_store(acc[f][reg], &out[oidx]);
            }
        }

        lgkm_barrier();

        // -- advance ring slots by 8 mod 18 --
#pragma unroll
        for (int m = 0; m < 4; ++m) {
            sl[m] += 8; if (sl[m] >= 18) sl[m] -= 18;
        }
        wb += 8; if (wb >= 18) wb -= 18;
    }
}

extern "C" void kernel_launch(void* const* d_in, const int* in_sizes, int n_in,
                              void* d_out, int out_size, void* d_ws, size_t ws_size,
                              hipStream_t stream) {
    const float* x = (const float*)d_in[0];
    const float* fw = (const float*)d_in[1];
    float* out = (float*)d_out;
    unsigned short* wbuf = (unsigned short*)d_ws;  // 18*1024 bf16 = 36864 B

    prep_kernel<<<dim3(4), 256, 0, stream>>>(fw, wbuf);
    conv_pipe<<<dim3(1024), 256, 0, stream>>>(x, wbuf, out);
}